// Round 1
// baseline (674.240 us; speedup 1.0000x reference)
//
#include <hip/hip_runtime.h>
#include <math.h>

#define B      32
#define S      4096
#define H      1024
#define NSPANS 16
#define NCLS   25

// ---------------------------------------------------------------------------
// K1: span-mean pooling. Grid (NSPANS, B), block 256.
// Each block handles one (batch, span). Thread t owns float4 at h = 4*t.
// Thread 0 re-derives validity with the torch "break at first (0,0)" rule and
// the batch's total token count; each block adds span_sum/total into pooled.
// ---------------------------------------------------------------------------
__global__ __launch_bounds__(256) void span_pool_kernel(
    const float* __restrict__ emb,       // [B,S,H]
    const int*   __restrict__ spans,     // [B,NSPANS,2]
    float*       __restrict__ pooled)    // [B,H]  (must be pre-zeroed)
{
    const int n = blockIdx.x;
    const int b = blockIdx.y;

    __shared__ int   sh_s0, sh_s1, sh_valid;
    __shared__ float sh_scale;

    if (threadIdx.x == 0) {
        int total = 0, valid = 0, s0 = 0, s1 = 0;
        for (int k = 0; k < NSPANS; ++k) {
            int a = spans[(b * NSPANS + k) * 2 + 0];
            int e = spans[(b * NSPANS + k) * 2 + 1];
            if (a == 0 && e == 0) break;   // torch 'break' semantics
            total += (e - a);
            if (k == n) { valid = 1; s0 = a; s1 = e; }
        }
        sh_valid = valid;
        sh_s0 = s0;
        sh_s1 = s1;
        sh_scale = (total > 0) ? (1.0f / (float)total) : 0.0f;
    }
    __syncthreads();

    if (!sh_valid) return;
    const int   s0    = sh_s0;
    const int   s1    = sh_s1;
    const float scale = sh_scale;

    const float4* base = (const float4*)(emb + (size_t)b * S * H);
    const int hv = threadIdx.x;            // float4 index within H: 0..255

    float4 acc = make_float4(0.f, 0.f, 0.f, 0.f);
    for (int t = s0; t < s1; ++t) {
        float4 v = base[(size_t)t * (H / 4) + hv];
        acc.x += v.x; acc.y += v.y; acc.z += v.z; acc.w += v.w;
    }

    float* dst = pooled + (size_t)b * H + hv * 4;
    atomicAdd(dst + 0, acc.x * scale);
    atomicAdd(dst + 1, acc.y * scale);
    atomicAdd(dst + 2, acc.z * scale);
    atomicAdd(dst + 3, acc.w * scale);
}

// ---------------------------------------------------------------------------
// K2: h = relu(pooled @ W1 + b1).  Grid B*4 blocks of 256; 4 blocks cover
// one batch's 1024 outputs. pooled row staged in LDS; dot down W1 columns
// (coalesced across j; W1 is L2-resident).
// ---------------------------------------------------------------------------
__global__ __launch_bounds__(256) void fc1_relu_kernel(
    const float* __restrict__ pooled,    // [B,H]
    const float* __restrict__ W1,        // [H,H] row-major
    const float* __restrict__ b1,        // [H]
    float*       __restrict__ hbuf)      // [B,H]
{
    const int b  = blockIdx.x >> 2;
    const int j  = ((blockIdx.x & 3) << 8) + threadIdx.x;

    __shared__ float pool_s[H];
    const float4* src  = (const float4*)(pooled + (size_t)b * H);
    float4*       dst4 = (float4*)pool_s;
    dst4[threadIdx.x] = src[threadIdx.x];
    __syncthreads();

    float acc = b1[j];
    const float* w = W1 + j;
    #pragma unroll 8
    for (int i = 0; i < H; ++i) {
        acc = fmaf(pool_s[i], w[(size_t)i * H], acc);
    }
    hbuf[(size_t)b * H + j] = fmaxf(acc, 0.0f);
}

// ---------------------------------------------------------------------------
// K3: out = sigmoid(h @ W2 + b2).  Grid (NCLS, B), block 256.
// Wave shuffle reduce (width 64) then LDS across the 4 waves.
// ---------------------------------------------------------------------------
__global__ __launch_bounds__(256) void fc2_sigmoid_kernel(
    const float* __restrict__ hbuf,      // [B,H]
    const float* __restrict__ W2,        // [H,NCLS]
    const float* __restrict__ b2,        // [NCLS]
    float*       __restrict__ out)       // [B,NCLS]
{
    const int c = blockIdx.x;
    const int b = blockIdx.y;

    const float* hrow = hbuf + (size_t)b * H;
    float partial = 0.0f;
    #pragma unroll
    for (int i = threadIdx.x; i < H; i += 256) {
        partial = fmaf(hrow[i], W2[(size_t)i * NCLS + c], partial);
    }

    #pragma unroll
    for (int off = 32; off > 0; off >>= 1)
        partial += __shfl_down(partial, off, 64);

    __shared__ float wsum[4];
    const int wave = threadIdx.x >> 6;
    const int lane = threadIdx.x & 63;
    if (lane == 0) wsum[wave] = partial;
    __syncthreads();

    if (threadIdx.x == 0) {
        float s = wsum[0] + wsum[1] + wsum[2] + wsum[3] + b2[c];
        out[(size_t)b * NCLS + c] = 1.0f / (1.0f + expf(-s));
    }
}

// ---------------------------------------------------------------------------
extern "C" void kernel_launch(void* const* d_in, const int* in_sizes, int n_in,
                              void* d_out, int out_size, void* d_ws, size_t ws_size,
                              hipStream_t stream) {
    const float* emb   = (const float*)d_in[0];
    const int*   spans = (const int*)  d_in[1];
    const float* W1    = (const float*)d_in[2];
    const float* b1    = (const float*)d_in[3];
    const float* W2    = (const float*)d_in[4];
    const float* b2    = (const float*)d_in[5];
    float*       out   = (float*)d_out;

    float* pooled = (float*)d_ws;          // B*H floats = 128 KB
    float* hbuf   = pooled + B * H;        // B*H floats = 128 KB

    // pooled must start from zero (ws is poisoned with 0xAA before each call)
    hipMemsetAsync(d_ws, 0, (size_t)B * H * sizeof(float), stream);

    span_pool_kernel<<<dim3(NSPANS, B), 256, 0, stream>>>(emb, spans, pooled);
    fc1_relu_kernel<<<dim3(B * 4), 256, 0, stream>>>(pooled, W1, b1, hbuf);
    fc2_sigmoid_kernel<<<dim3(NCLS, B), 256, 0, stream>>>(hbuf, W2, b2, out);
}